// Round 13
// baseline (238.191 us; speedup 1.0000x reference)
//
#include <hip/hip_runtime.h>
#include <hip/hip_bf16.h>

// Causal self-attention: qkv = x@w_qkv + b_qkv; flash-attn (causal); out = att@w_proj + b_proj
// B=4, T=2048, C=1024, H=16, D=64. All matmuls bf16 MFMA 16x16x32, fp32 accumulate.
// R13: gemm1 ported to the PROVEN 256²/8-wave/8-phase counted-vmcnt template (m201):
//      LDS [2][2][128][64] per op (128KB), 1 block/CU, per-wave C 128x64, per phase
//      {ds_read frags | stage 1 half-tile | barrier | 16 MFMA | barrier}, vmcnt(4)
//      at phases 3/7 only (never drains). Stage map proven region-safe (B-halves free
//      after q0, A-halves after q3). r8 (row&7) slot swizzle reused. proj GEMM and
//      flash unchanged (flash: launch_bounds 3->4 blocks/CU).

typedef __bf16 bf16x8 __attribute__((ext_vector_type(8)));
typedef float f32x4 __attribute__((ext_vector_type(4)));
typedef unsigned short u16x8 __attribute__((ext_vector_type(8)));
typedef unsigned short u16x4 __attribute__((ext_vector_type(4)));
typedef unsigned int u32;

#define LOG2E 1.44269504088896340736f
#define NEG_INF (-__builtin_inff())

#define AS_GLOBAL(p) ((const __attribute__((address_space(1))) u32*)(p))
#define AS_LDS(p) ((__attribute__((address_space(3))) u32*)(p))

__device__ __forceinline__ unsigned short f2bf(float f) {
  unsigned int u = __builtin_bit_cast(unsigned int, f);
  u += 0x7fff + ((u >> 16) & 1);   // RNE
  return (unsigned short)(u >> 16);
}

__device__ __forceinline__ u32 cvt_pk_bf16(float lo, float hi) {
  u32 r;
  asm("v_cvt_pk_bf16_f32 %0, %1, %2" : "=v"(r) : "v"(lo), "v"(hi));
  return r;
}

__device__ __forceinline__ bf16x8 ld_frag(const unsigned short* p) {
  return __builtin_bit_cast(bf16x8, *reinterpret_cast<const u16x8*>(p));
}

// ---- fp32 -> bf16 elementwise (x) ----
__global__ void k_convert(const float* __restrict__ in, unsigned short* __restrict__ out, int n4) {
  int i = blockIdx.x * blockDim.x + threadIdx.x;
  int stride = gridDim.x * blockDim.x;
  for (; i < n4; i += stride) {
    float4 v = reinterpret_cast<const float4*>(in)[i];
    u16x4 o = { f2bf(v.x), f2bf(v.y), f2bf(v.z), f2bf(v.w) };
    reinterpret_cast<u16x4*>(out)[i] = o;
  }
}

// ---- fp32 [K][N] -> bf16 [N][K] transpose; rows n < scaleN of output scaled by scl ----
__global__ void k_transpose(const float* __restrict__ in, unsigned short* __restrict__ out,
                            int K, int N, int scaleN, float scl) {
  __shared__ float tile[32][33];
  int n0 = blockIdx.x * 32, k0 = blockIdx.y * 32;
  int tx = threadIdx.x & 31, ty = threadIdx.x >> 5;  // 32 x 8
#pragma unroll
  for (int i = 0; i < 4; i++)
    tile[ty + i * 8][tx] = in[(size_t)(k0 + ty + i * 8) * N + n0 + tx];
  __syncthreads();
#pragma unroll
  for (int i = 0; i < 4; i++) {
    int n = n0 + ty + i * 8;
    float v = tile[tx][ty + i * 8];
    if (n < scaleN) v *= scl;
    out[(size_t)n * K + k0 + tx] = f2bf(v);
  }
}

// ---- bias prep: first scaleN entries scaled ----
__global__ void k_scale_bias(const float* __restrict__ in, float* __restrict__ out,
                             int n, int scaleN, float scl) {
  int i = blockIdx.x * blockDim.x + threadIdx.x;
  if (i < n) out[i] = (i < scaleN) ? in[i] * scl : in[i];
}

// ---- bf16 GEMM (r8-proven 128² 2-phase, for proj): C = A @ Bt^T + bias ----
template <bool BF16_OUT>
__global__ __launch_bounds__(256) void k_gemm(
    const unsigned short* __restrict__ A, const unsigned short* __restrict__ Bt,
    const float* __restrict__ bias, void* __restrict__ Cv, int M, int N, int K) {
  constexpr int BK = 64;
  __shared__ unsigned short Asm[128][BK];
  __shared__ unsigned short Bsm[128][BK];
  const int tid = threadIdx.x;
  const int lane = tid & 63, w = tid >> 6;
  const int wr = w >> 1, wc = w & 1;
  const int brow = blockIdx.x * 128, bcol = blockIdx.y * 128;
  const int r0 = lane & 15, kq = lane >> 4;

  f32x4 acc[4][4] = {};

  const int srow = lane >> 3;
  const int scol = ((lane & 7) ^ srow) * 8;
  const int swa = (r0 & 7) << 3;

  for (int k0 = 0; k0 < K; k0 += BK) {
    __syncthreads();
#pragma unroll
    for (int q2 = 0; q2 < 4; q2++) {
      int c = w * 4 + q2;
      const unsigned short* ga = &A[(size_t)(brow + c * 8 + srow) * K + k0 + scol];
      const unsigned short* gb = &Bt[(size_t)(bcol + c * 8 + srow) * K + k0 + scol];
      __builtin_amdgcn_global_load_lds(AS_GLOBAL(ga), AS_LDS(&Asm[c * 8][0]), 16, 0, 0);
      __builtin_amdgcn_global_load_lds(AS_GLOBAL(gb), AS_LDS(&Bsm[c * 8][0]), 16, 0, 0);
    }
    __syncthreads();
#pragma unroll
    for (int c = 0; c < 2; c++) {
      bf16x8 af[4], bfr[4];
#pragma unroll
      for (int m = 0; m < 4; m++)
        af[m] = ld_frag(&Asm[wr * 64 + m * 16 + r0][(c * 32 + kq * 8) ^ swa]);
#pragma unroll
      for (int n = 0; n < 4; n++)
        bfr[n] = ld_frag(&Bsm[wc * 64 + n * 16 + r0][(c * 32 + kq * 8) ^ swa]);
      __builtin_amdgcn_s_setprio(1);
#pragma unroll
      for (int m = 0; m < 4; m++)
#pragma unroll
        for (int n = 0; n < 4; n++)
          acc[m][n] = __builtin_amdgcn_mfma_f32_16x16x32_bf16(af[m], bfr[n], acc[m][n], 0, 0, 0);
      __builtin_amdgcn_s_setprio(0);
    }
  }

  const int orow = kq * 4;
#pragma unroll
  for (int n = 0; n < 4; n++) {
#pragma unroll
    for (int m = 0; m < 4; m++) {
      int col = bcol + wc * 64 + n * 16 + r0;
      float bv = bias[col];
#pragma unroll
      for (int r = 0; r < 4; r++) {
        int row = brow + wr * 64 + m * 16 + orow + r;
        float v = acc[m][n][r] + bv;
        if (BF16_OUT)
          ((unsigned short*)Cv)[(size_t)row * N + col] = f2bf(v);
        else
          ((float*)Cv)[(size_t)row * N + col] = v;
      }
    }
  }
}

// ---- bf16 GEMM 256² 8-wave 8-phase (qkv GEMM): C[M][N] = A @ Bt^T + bias, bf16 out ----
#define PBAR { __builtin_amdgcn_sched_barrier(0); __builtin_amdgcn_s_barrier(); \
               __builtin_amdgcn_sched_barrier(0); }
#define VM4 asm volatile("s_waitcnt vmcnt(4)" ::: "memory")

__global__ __launch_bounds__(512, 2) void k_gemm256(
    const unsigned short* __restrict__ A, const unsigned short* __restrict__ Bt,
    const float* __restrict__ bias, unsigned short* __restrict__ C, int M, int N, int K) {
  __shared__ __align__(16) unsigned short Asm[2][2][128][64];  // [buf][half][row][col]
  __shared__ __align__(16) unsigned short Bsm[2][2][128][64];
  const int tid = threadIdx.x, lane = tid & 63, w = tid >> 6;  // 8 waves
  const int wm = w >> 2, wn = w & 3;                           // 2M x 4N
  const int brow = blockIdx.x * 256, bcol = blockIdx.y * 256;
  const int r0 = lane & 15, kq = lane >> 4;
  const int prow = w * 16 + (lane >> 3);                // staging row (j=0) in half-plane
  const int scol = ((lane & 7) ^ (lane >> 3)) * 8;      // inverse-swizzled source slot

  f32x4 acc[8][4] = {};
  bf16x8 bfr[4][2];
  const int NT = K >> 6;  // 16

#define STGA(h, ts) { int ks = ((ts) < NT ? (ts) : 0) * 64; int bb_ = (ts) & 1;        \
    __builtin_amdgcn_global_load_lds(                                                  \
        AS_GLOBAL(&A[(size_t)(brow + (h) * 128 + prow) * K + ks + scol]),               \
        AS_LDS(&Asm[bb_][h][w * 16][0]), 16, 0, 0);                                     \
    __builtin_amdgcn_global_load_lds(                                                  \
        AS_GLOBAL(&A[(size_t)(brow + (h) * 128 + prow + 8) * K + ks + scol]),           \
        AS_LDS(&Asm[bb_][h][w * 16 + 8][0]), 16, 0, 0); }
#define STGB(h, ts) { int ks = ((ts) < NT ? (ts) : 0) * 64; int bb_ = (ts) & 1;        \
    __builtin_amdgcn_global_load_lds(                                                  \
        AS_GLOBAL(&Bt[(size_t)(bcol + (h) * 128 + prow) * K + ks + scol]),              \
        AS_LDS(&Bsm[bb_][h][w * 16][0]), 16, 0, 0);                                     \
    __builtin_amdgcn_global_load_lds(                                                  \
        AS_GLOBAL(&Bt[(size_t)(bcol + (h) * 128 + prow + 8) * K + ks + scol]),          \
        AS_LDS(&Bsm[bb_][h][w * 16 + 8][0]), 16, 0, 0); }
#define LDA_(bb, m, k) ld_frag(&Asm[bb][wm][(m) * 16 + r0][(((k) * 4 + kq) ^ (r0 & 7)) * 8])
#define LDB_(bb, n, k) \
  ld_frag(&Bsm[bb][wn >> 1][(wn & 1) * 64 + (n) * 16 + r0][(((k) * 4 + kq) ^ (r0 & 7)) * 8])

// one phase: read frags for m-pair q, (q==0: also B-frags), stage one half-tile,
// barrier, 16 MFMA, optional vmcnt, barrier.
#define PH(bb, q, STAGE, TAIL)                                                          \
  {                                                                                     \
    bf16x8 a00 = LDA_(bb, 2 * (q), 0);                                                  \
    bf16x8 a01 = LDA_(bb, 2 * (q), 1);                                                  \
    bf16x8 a10 = LDA_(bb, 2 * (q) + 1, 0);                                              \
    bf16x8 a11 = LDA_(bb, 2 * (q) + 1, 1);                                              \
    if ((q) == 0) {                                                                     \
      _Pragma("unroll") for (int n = 0; n < 4; ++n) {                                   \
        bfr[n][0] = LDB_(bb, n, 0);                                                     \
        bfr[n][1] = LDB_(bb, n, 1);                                                     \
      }                                                                                 \
    }                                                                                   \
    STAGE;                                                                              \
    PBAR;                                                                               \
    __builtin_amdgcn_s_setprio(1);                                                      \
    _Pragma("unroll") for (int n = 0; n < 4; ++n) {                                     \
      acc[2 * (q)][n] = __builtin_amdgcn_mfma_f32_16x16x32_bf16(a00, bfr[n][0], acc[2 * (q)][n], 0, 0, 0);         \
      acc[2 * (q) + 1][n] = __builtin_amdgcn_mfma_f32_16x16x32_bf16(a10, bfr[n][0], acc[2 * (q) + 1][n], 0, 0, 0); \
      acc[2 * (q)][n] = __builtin_amdgcn_mfma_f32_16x16x32_bf16(a01, bfr[n][1], acc[2 * (q)][n], 0, 0, 0);         \
      acc[2 * (q) + 1][n] = __builtin_amdgcn_mfma_f32_16x16x32_bf16(a11, bfr[n][1], acc[2 * (q) + 1][n], 0, 0, 0); \
    }                                                                                   \
    __builtin_amdgcn_s_setprio(0);                                                      \
    TAIL;                                                                               \
    PBAR;                                                                               \
  }

  // prologue: tile0 full + tile1 B-halves; keep B(1) in flight
  STGA(0, 0); STGA(1, 0); STGB(0, 0); STGB(1, 0); STGB(0, 1); STGB(1, 1);
  VM4;
  PBAR;

  const int NIT = NT >> 1;  // 8
  for (int i = 0; i < NIT; ++i) {
    const int t1 = 2 * i + 1, t2 = 2 * i + 2, t3 = 2 * i + 3;
    PH(0, 0, STGA(0, t1), (void)0);
    PH(0, 1, STGA(1, t1), (void)0);
    PH(0, 2, STGB(0, t2), (void)0);
    PH(0, 3, STGB(1, t2), VM4);
    PH(1, 0, STGA(0, t2), (void)0);
    PH(1, 1, STGA(1, t2), (void)0);
    PH(1, 2, STGB(0, t3), (void)0);
    PH(1, 3, STGB(1, t3), VM4);
  }

  // epilogue: bias + bf16 C write. acc rows: brow + wm*128 + m*16 + kq*4 + r
#pragma unroll
  for (int n = 0; n < 4; n++) {
    int col = bcol + wn * 64 + n * 16 + r0;
    float bv = bias[col];
#pragma unroll
    for (int m = 0; m < 8; m++) {
#pragma unroll
      for (int r = 0; r < 4; r++) {
        int row = brow + wm * 128 + m * 16 + kq * 4 + r;
        C[(size_t)row * N + col] = f2bf(acc[m][n][r] + bv);
      }
    }
  }
#undef STGA
#undef STGB
#undef LDA_
#undef LDB_
#undef PH
}

// ---- causal flash attention: 4 waves x 32 q-rows (2 subtiles), 128-row blocks ----
// Q pre-scaled by 0.125*log2e => S^T in log2 domain. Straight-line softmax (r12-proven).
__global__ __launch_bounds__(256, 4) void k_flash(const unsigned short* __restrict__ qkv,
                                                  unsigned short* __restrict__ att, int T) {
  constexpr int C3 = 3072, C = 1024;
  __shared__ unsigned short Ksm[2][64][72];   // [buf][tk][d]
  __shared__ unsigned short Vsm[2][64][72];   // [buf][d][tk ^ (d&56)]

  const int tid = threadIdx.x, lane = tid & 63, w = tid >> 6;
  const int bh = blockIdx.x;
  const int qtp = gridDim.y - 1 - blockIdx.y;  // long blocks first
  const int b = bh >> 4, h = bh & 15;
  const int q0 = qtp * 128;
  const int r0 = lane & 15, kq = lane >> 4;

  const size_t rowbase = (size_t)b * T * C3;
  const int qb0 = q0 + w * 32, qb1 = qb0 + 16;

  bf16x8 qf[2][2];
  {
    const unsigned short* qp0 = &qkv[rowbase + (size_t)(qb0 + r0) * C3 + h * 64];
    qf[0][0] = ld_frag(&qp0[kq * 8]);
    qf[0][1] = ld_frag(&qp0[32 + kq * 8]);
    const unsigned short* qp1 = qp0 + (size_t)16 * C3;
    qf[1][0] = ld_frag(&qp1[kq * 8]);
    qf[1][1] = ld_frag(&qp1[32 + kq * 8]);
  }

  f32x4 accO[2][4] = {};
  f32x4 ls4[2] = {{0.f,0.f,0.f,0.f},{0.f,0.f,0.f,0.f}};

  const int stk = tid >> 3, sd8 = (tid & 7) * 8;
  constexpr size_t PSTRIDE = (size_t)32 * C3;
  constexpr size_t TSTRIDE = (size_t)64 * C3;
  const unsigned short* kp0 = &qkv[rowbase + (size_t)stk * C3 + h * 64 + sd8 + C];
  const unsigned short* kp1 = kp0 + PSTRIDE;

  u16x8 kreg[2], vreg[2];
  auto LOADT = [&]() {
    kreg[0] = *reinterpret_cast<const u16x8*>(kp0);
    vreg[0] = *reinterpret_cast<const u16x8*>(kp0 + C);
    kreg[1] = *reinterpret_cast<const u16x8*>(kp1);
    vreg[1] = *reinterpret_cast<const u16x8*>(kp1 + C);
    kp0 += TSTRIDE;
    kp1 += TSTRIDE;
  };
  auto WRITET = [&](int buf) {
#pragma unroll
    for (int p = 0; p < 2; p++) {
      int tkk = p * 32 + stk;
      *reinterpret_cast<u16x8*>(&Ksm[buf][tkk][sd8]) = kreg[p];
      int tkx = tkk ^ sd8;
#pragma unroll
      for (int i = 0; i < 8; i++) Vsm[buf][sd8 + i][tkx] = vreg[p][i];
    }
  };

  auto TILE = [&](int buf, int k0) {
    if (k0 > qb1 + 15) return;
    const unsigned short(*Ks)[72] = Ksm[buf];
    const unsigned short(*Vs)[72] = Vsm[buf];

    f32x4 st[2][4];
    __builtin_amdgcn_s_setprio(1);
#pragma unroll
    for (int s = 0; s < 4; s++) {
      bf16x8 kf0 = ld_frag(&Ks[s * 16 + r0][kq * 8]);
      bf16x8 kf1 = ld_frag(&Ks[s * 16 + r0][32 + kq * 8]);
#pragma unroll
      for (int u = 0; u < 2; u++) {
        f32x4 a = {};
        a = __builtin_amdgcn_mfma_f32_16x16x32_bf16(kf0, qf[u][0], a, 0, 0, 0);
        a = __builtin_amdgcn_mfma_f32_16x16x32_bf16(kf1, qf[u][1], a, 0, 0, 0);
        st[u][s] = a;
      }
    }
    __builtin_amdgcn_s_setprio(0);

    u32 pd[2][2][4];
#pragma unroll
    for (int u = 0; u < 2; u++) {
      const int qbu = u ? qb1 : qb0;
      const int qmy = qbu + r0;
      f32x4 sv[4];
      if (k0 + 63 > qbu) {
#pragma unroll
        for (int s = 0; s < 4; s++)
#pragma unroll
          for (int r = 0; r < 4; r++) {
            int kg = k0 + s * 16 + kq * 4 + r;
            sv[s][r] = (kg > qmy) ? NEG_INF : st[u][s][r];
          }
      } else {
#pragma unroll
        for (int s = 0; s < 4; s++) sv[s] = st[u][s];
      }

#pragma unroll
      for (int s = 0; s < 4; s++) {
        f32x4 p = { exp2f(sv[s][0]), exp2f(sv[s][1]), exp2f(sv[s][2]), exp2f(sv[s][3]) };
        sv[s] = p;
        ls4[u] += p;
      }
      pd[u][0][0] = cvt_pk_bf16(sv[0][0], sv[0][1]);
      pd[u][0][1] = cvt_pk_bf16(sv[0][2], sv[0][3]);
      pd[u][0][2] = cvt_pk_bf16(sv[1][0], sv[1][1]);
      pd[u][0][3] = cvt_pk_bf16(sv[1][2], sv[1][3]);
      pd[u][1][0] = cvt_pk_bf16(sv[2][0], sv[2][1]);
      pd[u][1][1] = cvt_pk_bf16(sv[2][2], sv[2][3]);
      pd[u][1][2] = cvt_pk_bf16(sv[3][0], sv[3][1]);
      pd[u][1][3] = cvt_pk_bf16(sv[3][2], sv[3][3]);
    }

    __builtin_amdgcn_s_setprio(1);
#pragma unroll
    for (int t = 0; t < 2; t++) {
      bf16x8 pa0 = __builtin_bit_cast(bf16x8, *reinterpret_cast<u16x8*>(pd[0][t]));
      bf16x8 pa1 = __builtin_bit_cast(bf16x8, *reinterpret_cast<u16x8*>(pd[1][t]));
#pragma unroll
      for (int n = 0; n < 4; n++) {
        int d = n * 16 + r0;
        int swzb = d & 56;
        const u16x4 lo = *reinterpret_cast<const u16x4*>(&Vs[d][(t * 32 + kq * 4) ^ swzb]);
        const u16x4 hi = *reinterpret_cast<const u16x4*>(&Vs[d][(t * 32 + 16 + kq * 4) ^ swzb]);
        u16x8 vbw;
#pragma unroll
        for (int i = 0; i < 4; i++) { vbw[i] = lo[i]; vbw[4 + i] = hi[i]; }
        bf16x8 vb = __builtin_bit_cast(bf16x8, vbw);
        accO[0][n] = __builtin_amdgcn_mfma_f32_16x16x32_bf16(pa0, vb, accO[0][n], 0, 0, 0);
        accO[1][n] = __builtin_amdgcn_mfma_f32_16x16x32_bf16(pa1, vb, accO[1][n], 0, 0, 0);
      }
    }
    __builtin_amdgcn_s_setprio(0);
  };

  int buf = 0;
  LOADT();
  WRITET(0);
  const int nkt = (q0 + 128) >> 6;
  for (int kt = 0; kt < nkt - 1; kt++) {
    __syncthreads();
    LOADT();
    TILE(buf, kt * 64);
    WRITET(buf ^ 1);
    buf ^= 1;
  }
  __syncthreads();
  TILE(buf, (nkt - 1) * 64);

#pragma unroll
  for (int u = 0; u < 2; u++) {
    const int qbu = u ? qb1 : qb0;
    float l = ls4[u][0] + ls4[u][1] + ls4[u][2] + ls4[u][3];
    l += __shfl_xor(l, 16);
    l += __shfl_xor(l, 32);
    float lr[4];
#pragma unroll
    for (int r = 0; r < 4; r++) lr[r] = 1.f / __shfl(l, kq * 4 + r);
#pragma unroll
    for (int n = 0; n < 4; n++) {
#pragma unroll
      for (int r = 0; r < 4; r++) {
        int qrow = qbu + kq * 4 + r;
        float v = accO[u][n][r] * lr[r];
        att[((size_t)b * T + qrow) * C + h * 64 + n * 16 + r0] = f2bf(v);
      }
    }
  }
}

extern "C" void kernel_launch(void* const* d_in, const int* in_sizes, int n_in,
                              void* d_out, int out_size, void* d_ws, size_t ws_size,
                              hipStream_t stream) {
  const float* x = (const float*)d_in[0];
  const float* w_qkv = (const float*)d_in[1];
  const float* b_qkv = (const float*)d_in[2];
  const float* w_proj = (const float*)d_in[3];
  const float* b_proj = (const float*)d_in[4];

  constexpr int B = 4, T = 2048, C = 1024, C3 = 3072;
  constexpr int M = B * T;  // 8192
  constexpr float SCL = 0.125f * LOG2E;

  unsigned short* x_bf = (unsigned short*)d_ws;            // M*C
  unsigned short* wqkvT = x_bf + (size_t)M * C;            // C3*C
  unsigned short* wprojT = wqkvT + (size_t)C3 * C;         // C*C
  unsigned short* qkv = wprojT + (size_t)C * C;            // M*C3
  unsigned short* att = qkv + (size_t)M * C3;              // M*C
  float* bias_s = (float*)(att + (size_t)M * C);           // C3 floats

  hipLaunchKernelGGL(k_convert, dim3(2048), dim3(256), 0, stream, x, x_bf, M * C / 4);
  hipLaunchKernelGGL(k_transpose, dim3(C3 / 32, C / 32), dim3(256), 0, stream,
                     w_qkv, wqkvT, C, C3, C, SCL);
  hipLaunchKernelGGL(k_transpose, dim3(C / 32, C / 32), dim3(256), 0, stream,
                     w_proj, wprojT, C, C, 0, 1.f);
  hipLaunchKernelGGL(k_scale_bias, dim3((C3 + 255) / 256), dim3(256), 0, stream,
                     b_qkv, bias_s, C3, C, SCL);
  hipLaunchKernelGGL(k_gemm256, dim3(M / 256, C3 / 256), dim3(512), 0, stream,
                     x_bf, wqkvT, bias_s, qkv, M, C3, C);
  hipLaunchKernelGGL(k_flash, dim3(64, 16), dim3(256), 0, stream, qkv, att, T);
  hipLaunchKernelGGL((k_gemm<false>), dim3(M / 128, C / 128), dim3(256), 0, stream,
                     att, wprojT, b_proj, d_out, M, C, C);
}

// Round 14
// 194.577 us; speedup vs baseline: 1.2241x; 1.2241x over previous
//
#include <hip/hip_runtime.h>
#include <hip/hip_bf16.h>

// Causal self-attention: qkv = x@w_qkv + b_qkv; flash-attn (causal); out = att@w_proj + b_proj
// B=4, T=2048, C=1024, H=16, D=64. All matmuls bf16 MFMA 16x16x32, fp32 accumulate.
// R14: GEMMs reverted to r8-proven 128² 2-phase + (row&7) swizzle (8-phase closed: two
//      failed ports; at N=3072/K=1024 the 256² template hits a 1.5-round occupancy tail).
//      Flash: 512-thread / 8-wave blocks (256 q-rows) — staging per-thread halved,
//      16 waves/CU (vs 12). Per-wave structure identical to r12 (VGPR-safe, 84).
//      NOTE: launch_bounds 2nd arg >=5 on 256-thr flash caused VGPR squeeze->spills (r13).

typedef __bf16 bf16x8 __attribute__((ext_vector_type(8)));
typedef float f32x4 __attribute__((ext_vector_type(4)));
typedef unsigned short u16x8 __attribute__((ext_vector_type(8)));
typedef unsigned short u16x4 __attribute__((ext_vector_type(4)));
typedef unsigned int u32;

#define LOG2E 1.44269504088896340736f
#define NEG_INF (-__builtin_inff())

#define AS_GLOBAL(p) ((const __attribute__((address_space(1))) u32*)(p))
#define AS_LDS(p) ((__attribute__((address_space(3))) u32*)(p))

__device__ __forceinline__ unsigned short f2bf(float f) {
  unsigned int u = __builtin_bit_cast(unsigned int, f);
  u += 0x7fff + ((u >> 16) & 1);   // RNE
  return (unsigned short)(u >> 16);
}

__device__ __forceinline__ u32 cvt_pk_bf16(float lo, float hi) {
  u32 r;
  asm("v_cvt_pk_bf16_f32 %0, %1, %2" : "=v"(r) : "v"(lo), "v"(hi));
  return r;
}

__device__ __forceinline__ bf16x8 ld_frag(const unsigned short* p) {
  return __builtin_bit_cast(bf16x8, *reinterpret_cast<const u16x8*>(p));
}

// ---- fp32 -> bf16 elementwise (x) ----
__global__ void k_convert(const float* __restrict__ in, unsigned short* __restrict__ out, int n4) {
  int i = blockIdx.x * blockDim.x + threadIdx.x;
  int stride = gridDim.x * blockDim.x;
  for (; i < n4; i += stride) {
    float4 v = reinterpret_cast<const float4*>(in)[i];
    u16x4 o = { f2bf(v.x), f2bf(v.y), f2bf(v.z), f2bf(v.w) };
    reinterpret_cast<u16x4*>(out)[i] = o;
  }
}

// ---- fp32 [K][N] -> bf16 [N][K] transpose; rows n < scaleN of output scaled by scl ----
__global__ void k_transpose(const float* __restrict__ in, unsigned short* __restrict__ out,
                            int K, int N, int scaleN, float scl) {
  __shared__ float tile[32][33];
  int n0 = blockIdx.x * 32, k0 = blockIdx.y * 32;
  int tx = threadIdx.x & 31, ty = threadIdx.x >> 5;  // 32 x 8
#pragma unroll
  for (int i = 0; i < 4; i++)
    tile[ty + i * 8][tx] = in[(size_t)(k0 + ty + i * 8) * N + n0 + tx];
  __syncthreads();
#pragma unroll
  for (int i = 0; i < 4; i++) {
    int n = n0 + ty + i * 8;
    float v = tile[tx][ty + i * 8];
    if (n < scaleN) v *= scl;
    out[(size_t)n * K + k0 + tx] = f2bf(v);
  }
}

// ---- bias prep: first scaleN entries scaled ----
__global__ void k_scale_bias(const float* __restrict__ in, float* __restrict__ out,
                             int n, int scaleN, float scl) {
  int i = blockIdx.x * blockDim.x + threadIdx.x;
  if (i < n) out[i] = (i < scaleN) ? in[i] * scl : in[i];
}

// ---- bf16 GEMM (r8-proven: m97 structure + correct T2 swizzle) ----
// LDS (row, slot) holds global (row, slot ^ (row&7)); slot = 8-elem (16B) unit.
template <bool BF16_OUT>
__global__ __launch_bounds__(256) void k_gemm(
    const unsigned short* __restrict__ A, const unsigned short* __restrict__ Bt,
    const float* __restrict__ bias, void* __restrict__ Cv, int M, int N, int K) {
  constexpr int BK = 64;
  __shared__ unsigned short Asm[128][BK];
  __shared__ unsigned short Bsm[128][BK];
  const int tid = threadIdx.x;
  const int lane = tid & 63, w = tid >> 6;
  const int wr = w >> 1, wc = w & 1;
  const int brow = blockIdx.x * 128, bcol = blockIdx.y * 128;
  const int r0 = lane & 15, kq = lane >> 4;

  f32x4 acc[4][4] = {};

  const int srow = lane >> 3;
  const int scol = ((lane & 7) ^ srow) * 8;
  const int swa = (r0 & 7) << 3;

  for (int k0 = 0; k0 < K; k0 += BK) {
    __syncthreads();
#pragma unroll
    for (int q2 = 0; q2 < 4; q2++) {
      int c = w * 4 + q2;
      const unsigned short* ga = &A[(size_t)(brow + c * 8 + srow) * K + k0 + scol];
      const unsigned short* gb = &Bt[(size_t)(bcol + c * 8 + srow) * K + k0 + scol];
      __builtin_amdgcn_global_load_lds(AS_GLOBAL(ga), AS_LDS(&Asm[c * 8][0]), 16, 0, 0);
      __builtin_amdgcn_global_load_lds(AS_GLOBAL(gb), AS_LDS(&Bsm[c * 8][0]), 16, 0, 0);
    }
    __syncthreads();
#pragma unroll
    for (int c = 0; c < 2; c++) {
      bf16x8 af[4], bfr[4];
#pragma unroll
      for (int m = 0; m < 4; m++)
        af[m] = ld_frag(&Asm[wr * 64 + m * 16 + r0][(c * 32 + kq * 8) ^ swa]);
#pragma unroll
      for (int n = 0; n < 4; n++)
        bfr[n] = ld_frag(&Bsm[wc * 64 + n * 16 + r0][(c * 32 + kq * 8) ^ swa]);
      __builtin_amdgcn_s_setprio(1);
#pragma unroll
      for (int m = 0; m < 4; m++)
#pragma unroll
        for (int n = 0; n < 4; n++)
          acc[m][n] = __builtin_amdgcn_mfma_f32_16x16x32_bf16(af[m], bfr[n], acc[m][n], 0, 0, 0);
      __builtin_amdgcn_s_setprio(0);
    }
  }

  const int orow = kq * 4;
#pragma unroll
  for (int n = 0; n < 4; n++) {
#pragma unroll
    for (int m = 0; m < 4; m++) {
      int col = bcol + wc * 64 + n * 16 + r0;
      float bv = bias[col];
#pragma unroll
      for (int r = 0; r < 4; r++) {
        int row = brow + wr * 64 + m * 16 + orow + r;
        float v = acc[m][n][r] + bv;
        if (BF16_OUT)
          ((unsigned short*)Cv)[(size_t)row * N + col] = f2bf(v);
        else
          ((float*)Cv)[(size_t)row * N + col] = v;
      }
    }
  }
}

// ---- causal flash attention: 8 waves x 32 q-rows, 256-row blocks, 512 threads ----
// Q pre-scaled by 0.125*log2e => S^T in log2 domain. Straight-line softmax (r12-proven).
// Staging divided over 512 threads (per-thread work halved vs 256-thread version).
__global__ __launch_bounds__(512, 4) void k_flash(const unsigned short* __restrict__ qkv,
                                                  unsigned short* __restrict__ att, int T) {
  constexpr int C3 = 3072, C = 1024;
  __shared__ unsigned short Ksm[2][64][72];   // [buf][tk][d]
  __shared__ unsigned short Vsm[2][64][72];   // [buf][d][tk ^ (d&56)]

  const int tid = threadIdx.x, lane = tid & 63, w = tid >> 6;  // 8 waves
  const int bh = blockIdx.x;
  const int qtp = gridDim.y - 1 - blockIdx.y;  // long blocks first
  const int b = bh >> 4, h = bh & 15;
  const int q0 = qtp * 256;
  const int r0 = lane & 15, kq = lane >> 4;

  const size_t rowbase = (size_t)b * T * C3;
  const int qb0 = q0 + w * 32, qb1 = qb0 + 16;

  bf16x8 qf[2][2];
  {
    const unsigned short* qp0 = &qkv[rowbase + (size_t)(qb0 + r0) * C3 + h * 64];
    qf[0][0] = ld_frag(&qp0[kq * 8]);
    qf[0][1] = ld_frag(&qp0[32 + kq * 8]);
    const unsigned short* qp1 = qp0 + (size_t)16 * C3;
    qf[1][0] = ld_frag(&qp1[kq * 8]);
    qf[1][1] = ld_frag(&qp1[32 + kq * 8]);
  }

  f32x4 accO[2][4] = {};
  f32x4 ls4[2] = {{0.f,0.f,0.f,0.f},{0.f,0.f,0.f,0.f}};

  const int stk = tid >> 3, sd8 = (tid & 7) * 8;   // 512 threads cover all 64 rows x 64 cols
  constexpr size_t TSTRIDE = (size_t)64 * C3;
  const unsigned short* kp = &qkv[rowbase + (size_t)stk * C3 + h * 64 + sd8 + C];

  u16x8 kreg, vreg;
  auto LOADT = [&]() {
    kreg = *reinterpret_cast<const u16x8*>(kp);
    vreg = *reinterpret_cast<const u16x8*>(kp + C);
    kp += TSTRIDE;
  };
  auto WRITET = [&](int buf) {
    *reinterpret_cast<u16x8*>(&Ksm[buf][stk][sd8]) = kreg;
    int tkx = stk ^ sd8;  // (d&56)==sd8 for all 8 d in this vector
#pragma unroll
    for (int i = 0; i < 8; i++) Vsm[buf][sd8 + i][tkx] = vreg[i];
  };

  auto TILE = [&](int buf, int k0) {
    if (k0 > qb1 + 15) return;   // whole wave past its causal range
    const unsigned short(*Ks)[72] = Ksm[buf];
    const unsigned short(*Vs)[72] = Vsm[buf];

    // S^T = K @ Q^T for both subtiles, K-frags shared
    f32x4 st[2][4];
    __builtin_amdgcn_s_setprio(1);
#pragma unroll
    for (int s = 0; s < 4; s++) {
      bf16x8 kf0 = ld_frag(&Ks[s * 16 + r0][kq * 8]);
      bf16x8 kf1 = ld_frag(&Ks[s * 16 + r0][32 + kq * 8]);
#pragma unroll
      for (int u = 0; u < 2; u++) {
        f32x4 a = {};
        a = __builtin_amdgcn_mfma_f32_16x16x32_bf16(kf0, qf[u][0], a, 0, 0, 0);
        a = __builtin_amdgcn_mfma_f32_16x16x32_bf16(kf1, qf[u][1], a, 0, 0, 0);
        st[u][s] = a;
      }
    }
    __builtin_amdgcn_s_setprio(0);

    // straight-line softmax: P = exp2(S) (mask -> 0), accumulate l
    u32 pd[2][2][4];
#pragma unroll
    for (int u = 0; u < 2; u++) {
      const int qbu = u ? qb1 : qb0;
      const int qmy = qbu + r0;
      f32x4 sv[4];
      if (k0 + 63 > qbu) {
#pragma unroll
        for (int s = 0; s < 4; s++)
#pragma unroll
          for (int r = 0; r < 4; r++) {
            int kg = k0 + s * 16 + kq * 4 + r;
            sv[s][r] = (kg > qmy) ? NEG_INF : st[u][s][r];
          }
      } else {
#pragma unroll
        for (int s = 0; s < 4; s++) sv[s] = st[u][s];
      }

#pragma unroll
      for (int s = 0; s < 4; s++) {
        f32x4 p = { exp2f(sv[s][0]), exp2f(sv[s][1]), exp2f(sv[s][2]), exp2f(sv[s][3]) };
        sv[s] = p;
        ls4[u] += p;
      }
      pd[u][0][0] = cvt_pk_bf16(sv[0][0], sv[0][1]);
      pd[u][0][1] = cvt_pk_bf16(sv[0][2], sv[0][3]);
      pd[u][0][2] = cvt_pk_bf16(sv[1][0], sv[1][1]);
      pd[u][0][3] = cvt_pk_bf16(sv[1][2], sv[1][3]);
      pd[u][1][0] = cvt_pk_bf16(sv[2][0], sv[2][1]);
      pd[u][1][1] = cvt_pk_bf16(sv[2][2], sv[2][3]);
      pd[u][1][2] = cvt_pk_bf16(sv[3][0], sv[3][1]);
      pd[u][1][3] = cvt_pk_bf16(sv[3][2], sv[3][3]);
    }

    // PV for both subtiles, V-frags shared
    __builtin_amdgcn_s_setprio(1);
#pragma unroll
    for (int t = 0; t < 2; t++) {
      bf16x8 pa0 = __builtin_bit_cast(bf16x8, *reinterpret_cast<u16x8*>(pd[0][t]));
      bf16x8 pa1 = __builtin_bit_cast(bf16x8, *reinterpret_cast<u16x8*>(pd[1][t]));
#pragma unroll
      for (int n = 0; n < 4; n++) {
        int d = n * 16 + r0;
        int swzb = d & 56;
        const u16x4 lo = *reinterpret_cast<const u16x4*>(&Vs[d][(t * 32 + kq * 4) ^ swzb]);
        const u16x4 hi = *reinterpret_cast<const u16x4*>(&Vs[d][(t * 32 + 16 + kq * 4) ^ swzb]);
        u16x8 vbw;
#pragma unroll
        for (int i = 0; i < 4; i++) { vbw[i] = lo[i]; vbw[4 + i] = hi[i]; }
        bf16x8 vb = __builtin_bit_cast(bf16x8, vbw);
        accO[0][n] = __builtin_amdgcn_mfma_f32_16x16x32_bf16(pa0, vb, accO[0][n], 0, 0, 0);
        accO[1][n] = __builtin_amdgcn_mfma_f32_16x16x32_bf16(pa1, vb, accO[1][n], 0, 0, 0);
      }
    }
    __builtin_amdgcn_s_setprio(0);
  };

  int buf = 0;
  LOADT();
  WRITET(0);
  const int nkt = (q0 + 256) >> 6;
  for (int kt = 0; kt < nkt - 1; kt++) {
    __syncthreads();
    LOADT();
    TILE(buf, kt * 64);
    WRITET(buf ^ 1);
    buf ^= 1;
  }
  __syncthreads();
  TILE(buf, (nkt - 1) * 64);

  // epilogue
#pragma unroll
  for (int u = 0; u < 2; u++) {
    const int qbu = u ? qb1 : qb0;
    float l = ls4[u][0] + ls4[u][1] + ls4[u][2] + ls4[u][3];
    l += __shfl_xor(l, 16);
    l += __shfl_xor(l, 32);
    float lr[4];
#pragma unroll
    for (int r = 0; r < 4; r++) lr[r] = 1.f / __shfl(l, kq * 4 + r);
#pragma unroll
    for (int n = 0; n < 4; n++) {
#pragma unroll
      for (int r = 0; r < 4; r++) {
        int qrow = qbu + kq * 4 + r;
        float v = accO[u][n][r] * lr[r];
        att[((size_t)b * T + qrow) * C + h * 64 + n * 16 + r0] = f2bf(v);
      }
    }
  }
}

extern "C" void kernel_launch(void* const* d_in, const int* in_sizes, int n_in,
                              void* d_out, int out_size, void* d_ws, size_t ws_size,
                              hipStream_t stream) {
  const float* x = (const float*)d_in[0];
  const float* w_qkv = (const float*)d_in[1];
  const float* b_qkv = (const float*)d_in[2];
  const float* w_proj = (const float*)d_in[3];
  const float* b_proj = (const float*)d_in[4];

  constexpr int B = 4, T = 2048, C = 1024, C3 = 3072;
  constexpr int M = B * T;  // 8192
  constexpr float SCL = 0.125f * LOG2E;

  unsigned short* x_bf = (unsigned short*)d_ws;            // M*C
  unsigned short* wqkvT = x_bf + (size_t)M * C;            // C3*C
  unsigned short* wprojT = wqkvT + (size_t)C3 * C;         // C*C
  unsigned short* qkv = wprojT + (size_t)C * C;            // M*C3
  unsigned short* att = qkv + (size_t)M * C3;              // M*C
  float* bias_s = (float*)(att + (size_t)M * C);           // C3 floats

  hipLaunchKernelGGL(k_convert, dim3(2048), dim3(256), 0, stream, x, x_bf, M * C / 4);
  hipLaunchKernelGGL(k_transpose, dim3(C3 / 32, C / 32), dim3(256), 0, stream,
                     w_qkv, wqkvT, C, C3, C, SCL);
  hipLaunchKernelGGL(k_transpose, dim3(C / 32, C / 32), dim3(256), 0, stream,
                     w_proj, wprojT, C, C, 0, 1.f);
  hipLaunchKernelGGL(k_scale_bias, dim3((C3 + 255) / 256), dim3(256), 0, stream,
                     b_qkv, bias_s, C3, C, SCL);
  hipLaunchKernelGGL((k_gemm<true>), dim3(M / 128, C3 / 128), dim3(256), 0, stream,
                     x_bf, wqkvT, bias_s, (void*)qkv, M, C3, C);
  hipLaunchKernelGGL(k_flash, dim3(64, 8), dim3(512), 0, stream, qkv, att, T);
  hipLaunchKernelGGL((k_gemm<false>), dim3(M / 128, C / 128), dim3(256), 0, stream,
                     att, wprojT, b_proj, d_out, M, C, C);
}

// Round 15
// 156.613 us; speedup vs baseline: 1.5209x; 1.2424x over previous
//
#include <hip/hip_runtime.h>
#include <hip/hip_bf16.h>

// Causal self-attention: qkv = x@w_qkv + b_qkv; flash-attn (causal); out = att@w_proj + b_proj
// B=4, T=2048, C=1024, H=16, D=64. All matmuls bf16 MFMA 16x16x32, fp32 accumulate.
// R15: flash reverted to r12-proven 256-thread structure (512-thr + launch_bounds w>=4
//      forced the 64-VGPR tier -> spills, twice). NEW: ones-column trick — softmax
//      denominator via MFMA (acc_l = mfma(pa, ones, acc_l)): moves l-accumulation from
//      the saturated VALU pipe to the idle MFMA pipe AND kills the epilogue shfl-reduce
//      (MFMA k-sum = cross-lane reduction; acc_l[u][r] holds l[q=kq*4+r] in-place).
//      k_scale_bias folded into the w_qkv transpose. GEMMs: r8-proven 2-phase+swizzle.

typedef __bf16 bf16x8 __attribute__((ext_vector_type(8)));
typedef float f32x4 __attribute__((ext_vector_type(4)));
typedef unsigned short u16x8 __attribute__((ext_vector_type(8)));
typedef unsigned short u16x4 __attribute__((ext_vector_type(4)));
typedef unsigned int u32;

#define LOG2E 1.44269504088896340736f
#define NEG_INF (-__builtin_inff())

#define AS_GLOBAL(p) ((const __attribute__((address_space(1))) u32*)(p))
#define AS_LDS(p) ((__attribute__((address_space(3))) u32*)(p))

__device__ __forceinline__ unsigned short f2bf(float f) {
  unsigned int u = __builtin_bit_cast(unsigned int, f);
  u += 0x7fff + ((u >> 16) & 1);   // RNE
  return (unsigned short)(u >> 16);
}

__device__ __forceinline__ u32 cvt_pk_bf16(float lo, float hi) {
  u32 r;
  asm("v_cvt_pk_bf16_f32 %0, %1, %2" : "=v"(r) : "v"(lo), "v"(hi));
  return r;
}

__device__ __forceinline__ bf16x8 ld_frag(const unsigned short* p) {
  return __builtin_bit_cast(bf16x8, *reinterpret_cast<const u16x8*>(p));
}

// ---- fp32 -> bf16 elementwise (x) ----
__global__ void k_convert(const float* __restrict__ in, unsigned short* __restrict__ out, int n4) {
  int i = blockIdx.x * blockDim.x + threadIdx.x;
  int stride = gridDim.x * blockDim.x;
  for (; i < n4; i += stride) {
    float4 v = reinterpret_cast<const float4*>(in)[i];
    u16x4 o = { f2bf(v.x), f2bf(v.y), f2bf(v.z), f2bf(v.w) };
    reinterpret_cast<u16x4*>(out)[i] = o;
  }
}

// ---- fp32 [K][N] -> bf16 [N][K] transpose; rows n < scaleN scaled by scl.
//      Optionally emits scaled bias (bias_out[n] = bias_in[n] * (n<scaleN ? scl : 1)). ----
__global__ void k_transpose(const float* __restrict__ in, unsigned short* __restrict__ out,
                            int K, int N, int scaleN, float scl,
                            const float* __restrict__ bias_in, float* __restrict__ bias_out) {
  __shared__ float tile[32][33];
  int n0 = blockIdx.x * 32, k0 = blockIdx.y * 32;
  int tx = threadIdx.x & 31, ty = threadIdx.x >> 5;  // 32 x 8
#pragma unroll
  for (int i = 0; i < 4; i++)
    tile[ty + i * 8][tx] = in[(size_t)(k0 + ty + i * 8) * N + n0 + tx];
  if (bias_out && k0 == 0 && ty == 0) {
    int n = n0 + tx;
    bias_out[n] = bias_in[n] * (n < scaleN ? scl : 1.f);
  }
  __syncthreads();
#pragma unroll
  for (int i = 0; i < 4; i++) {
    int n = n0 + ty + i * 8;
    float v = tile[tx][ty + i * 8];
    if (n < scaleN) v *= scl;
    out[(size_t)n * K + k0 + tx] = f2bf(v);
  }
}

// ---- bf16 GEMM (r8-proven: m97 structure + correct T2 swizzle) ----
// LDS (row, slot) holds global (row, slot ^ (row&7)); slot = 8-elem (16B) unit.
template <bool BF16_OUT>
__global__ __launch_bounds__(256) void k_gemm(
    const unsigned short* __restrict__ A, const unsigned short* __restrict__ Bt,
    const float* __restrict__ bias, void* __restrict__ Cv, int M, int N, int K) {
  constexpr int BK = 64;
  __shared__ unsigned short Asm[128][BK];
  __shared__ unsigned short Bsm[128][BK];
  const int tid = threadIdx.x;
  const int lane = tid & 63, w = tid >> 6;
  const int wr = w >> 1, wc = w & 1;
  const int brow = blockIdx.x * 128, bcol = blockIdx.y * 128;
  const int r0 = lane & 15, kq = lane >> 4;

  f32x4 acc[4][4] = {};

  const int srow = lane >> 3;
  const int scol = ((lane & 7) ^ srow) * 8;
  const int swa = (r0 & 7) << 3;

  for (int k0 = 0; k0 < K; k0 += BK) {
    __syncthreads();
#pragma unroll
    for (int q2 = 0; q2 < 4; q2++) {
      int c = w * 4 + q2;
      const unsigned short* ga = &A[(size_t)(brow + c * 8 + srow) * K + k0 + scol];
      const unsigned short* gb = &Bt[(size_t)(bcol + c * 8 + srow) * K + k0 + scol];
      __builtin_amdgcn_global_load_lds(AS_GLOBAL(ga), AS_LDS(&Asm[c * 8][0]), 16, 0, 0);
      __builtin_amdgcn_global_load_lds(AS_GLOBAL(gb), AS_LDS(&Bsm[c * 8][0]), 16, 0, 0);
    }
    __syncthreads();
#pragma unroll
    for (int c = 0; c < 2; c++) {
      bf16x8 af[4], bfr[4];
#pragma unroll
      for (int m = 0; m < 4; m++)
        af[m] = ld_frag(&Asm[wr * 64 + m * 16 + r0][(c * 32 + kq * 8) ^ swa]);
#pragma unroll
      for (int n = 0; n < 4; n++)
        bfr[n] = ld_frag(&Bsm[wc * 64 + n * 16 + r0][(c * 32 + kq * 8) ^ swa]);
      __builtin_amdgcn_s_setprio(1);
#pragma unroll
      for (int m = 0; m < 4; m++)
#pragma unroll
        for (int n = 0; n < 4; n++)
          acc[m][n] = __builtin_amdgcn_mfma_f32_16x16x32_bf16(af[m], bfr[n], acc[m][n], 0, 0, 0);
      __builtin_amdgcn_s_setprio(0);
    }
  }

  const int orow = kq * 4;
#pragma unroll
  for (int n = 0; n < 4; n++) {
#pragma unroll
    for (int m = 0; m < 4; m++) {
      int col = bcol + wc * 64 + n * 16 + r0;
      float bv = bias[col];
#pragma unroll
      for (int r = 0; r < 4; r++) {
        int row = brow + wr * 64 + m * 16 + orow + r;
        float v = acc[m][n][r] + bv;
        if (BF16_OUT)
          ((unsigned short*)Cv)[(size_t)row * N + col] = f2bf(v);
        else
          ((float*)Cv)[(size_t)row * N + col] = v;
      }
    }
  }
}

// ---- causal flash attention: 4 waves x 32 q-rows (2 subtiles), 128-row blocks ----
// Q pre-scaled by 0.125*log2e => S^T in log2 domain. Straight-line softmax (r12).
// Denominator via ones-column MFMA: acc_l[u][r] = l[q = kq*4+r] (no shfl reduce).
__global__ __launch_bounds__(256, 3) void k_flash(const unsigned short* __restrict__ qkv,
                                                  unsigned short* __restrict__ att, int T) {
  constexpr int C3 = 3072, C = 1024;
  __shared__ unsigned short Ksm[2][64][72];   // [buf][tk][d]
  __shared__ unsigned short Vsm[2][64][72];   // [buf][d][tk ^ (d&56)]

  const int tid = threadIdx.x, lane = tid & 63, w = tid >> 6;
  const int bh = blockIdx.x;
  const int qtp = gridDim.y - 1 - blockIdx.y;  // long blocks first
  const int b = bh >> 4, h = bh & 15;
  const int q0 = qtp * 128;
  const int r0 = lane & 15, kq = lane >> 4;

  const size_t rowbase = (size_t)b * T * C3;
  const int qb0 = q0 + w * 32, qb1 = qb0 + 16;

  bf16x8 qf[2][2];
  {
    const unsigned short* qp0 = &qkv[rowbase + (size_t)(qb0 + r0) * C3 + h * 64];
    qf[0][0] = ld_frag(&qp0[kq * 8]);
    qf[0][1] = ld_frag(&qp0[32 + kq * 8]);
    const unsigned short* qp1 = qp0 + (size_t)16 * C3;
    qf[1][0] = ld_frag(&qp1[kq * 8]);
    qf[1][1] = ld_frag(&qp1[32 + kq * 8]);
  }

  // ones vector for the denominator MFMA (bf16 1.0 = 0x3F80)
  u16x8 ones_w;
#pragma unroll
  for (int i = 0; i < 8; i++) ones_w[i] = 0x3F80;
  const bf16x8 ones8 = __builtin_bit_cast(bf16x8, ones_w);

  f32x4 accO[2][4] = {};
  f32x4 accl[2] = {{0.f,0.f,0.f,0.f},{0.f,0.f,0.f,0.f}};

  const int stk = tid >> 3, sd8 = (tid & 7) * 8;
  constexpr size_t PSTRIDE = (size_t)32 * C3;
  constexpr size_t TSTRIDE = (size_t)64 * C3;
  const unsigned short* kp0 = &qkv[rowbase + (size_t)stk * C3 + h * 64 + sd8 + C];
  const unsigned short* kp1 = kp0 + PSTRIDE;

  u16x8 kreg[2], vreg[2];
  auto LOADT = [&]() {
    kreg[0] = *reinterpret_cast<const u16x8*>(kp0);
    vreg[0] = *reinterpret_cast<const u16x8*>(kp0 + C);
    kreg[1] = *reinterpret_cast<const u16x8*>(kp1);
    vreg[1] = *reinterpret_cast<const u16x8*>(kp1 + C);
    kp0 += TSTRIDE;
    kp1 += TSTRIDE;
  };
  auto WRITET = [&](int buf) {
#pragma unroll
    for (int p = 0; p < 2; p++) {
      int tkk = p * 32 + stk;
      *reinterpret_cast<u16x8*>(&Ksm[buf][tkk][sd8]) = kreg[p];
      int tkx = tkk ^ sd8;
#pragma unroll
      for (int i = 0; i < 8; i++) Vsm[buf][sd8 + i][tkx] = vreg[p][i];
    }
  };

  auto TILE = [&](int buf, int k0) {
    if (k0 > qb1 + 15) return;   // whole wave past its causal range
    const unsigned short(*Ks)[72] = Ksm[buf];
    const unsigned short(*Vs)[72] = Vsm[buf];

    // S^T = K @ Q^T for both subtiles, K-frags shared
    f32x4 st[2][4];
    __builtin_amdgcn_s_setprio(1);
#pragma unroll
    for (int s = 0; s < 4; s++) {
      bf16x8 kf0 = ld_frag(&Ks[s * 16 + r0][kq * 8]);
      bf16x8 kf1 = ld_frag(&Ks[s * 16 + r0][32 + kq * 8]);
#pragma unroll
      for (int u = 0; u < 2; u++) {
        f32x4 a = {};
        a = __builtin_amdgcn_mfma_f32_16x16x32_bf16(kf0, qf[u][0], a, 0, 0, 0);
        a = __builtin_amdgcn_mfma_f32_16x16x32_bf16(kf1, qf[u][1], a, 0, 0, 0);
        st[u][s] = a;
      }
    }
    __builtin_amdgcn_s_setprio(0);

    // straight-line softmax: P = exp2(S) (mask -> 0); no l accumulation here
    u32 pd[2][2][4];
#pragma unroll
    for (int u = 0; u < 2; u++) {
      const int qbu = u ? qb1 : qb0;
      const int qmy = qbu + r0;
      f32x4 sv[4];
      if (k0 + 63 > qbu) {
#pragma unroll
        for (int s = 0; s < 4; s++)
#pragma unroll
          for (int r = 0; r < 4; r++) {
            int kg = k0 + s * 16 + kq * 4 + r;
            sv[s][r] = (kg > qmy) ? NEG_INF : st[u][s][r];
          }
      } else {
#pragma unroll
        for (int s = 0; s < 4; s++) sv[s] = st[u][s];
      }

#pragma unroll
      for (int s = 0; s < 4; s++) {
        f32x4 p = { exp2f(sv[s][0]), exp2f(sv[s][1]), exp2f(sv[s][2]), exp2f(sv[s][3]) };
        sv[s] = p;
      }
      pd[u][0][0] = cvt_pk_bf16(sv[0][0], sv[0][1]);
      pd[u][0][1] = cvt_pk_bf16(sv[0][2], sv[0][3]);
      pd[u][0][2] = cvt_pk_bf16(sv[1][0], sv[1][1]);
      pd[u][0][3] = cvt_pk_bf16(sv[1][2], sv[1][3]);
      pd[u][1][0] = cvt_pk_bf16(sv[2][0], sv[2][1]);
      pd[u][1][1] = cvt_pk_bf16(sv[2][2], sv[2][3]);
      pd[u][1][2] = cvt_pk_bf16(sv[3][0], sv[3][1]);
      pd[u][1][3] = cvt_pk_bf16(sv[3][2], sv[3][3]);
    }

    // PV + denominator (ones-column) for both subtiles, V-frags shared
    __builtin_amdgcn_s_setprio(1);
#pragma unroll
    for (int t = 0; t < 2; t++) {
      bf16x8 pa0 = __builtin_bit_cast(bf16x8, *reinterpret_cast<u16x8*>(pd[0][t]));
      bf16x8 pa1 = __builtin_bit_cast(bf16x8, *reinterpret_cast<u16x8*>(pd[1][t]));
      accl[0] = __builtin_amdgcn_mfma_f32_16x16x32_bf16(pa0, ones8, accl[0], 0, 0, 0);
      accl[1] = __builtin_amdgcn_mfma_f32_16x16x32_bf16(pa1, ones8, accl[1], 0, 0, 0);
#pragma unroll
      for (int n = 0; n < 4; n++) {
        int d = n * 16 + r0;
        int swzb = d & 56;
        const u16x4 lo = *reinterpret_cast<const u16x4*>(&Vs[d][(t * 32 + kq * 4) ^ swzb]);
        const u16x4 hi = *reinterpret_cast<const u16x4*>(&Vs[d][(t * 32 + 16 + kq * 4) ^ swzb]);
        u16x8 vbw;
#pragma unroll
        for (int i = 0; i < 4; i++) { vbw[i] = lo[i]; vbw[4 + i] = hi[i]; }
        bf16x8 vb = __builtin_bit_cast(bf16x8, vbw);
        accO[0][n] = __builtin_amdgcn_mfma_f32_16x16x32_bf16(pa0, vb, accO[0][n], 0, 0, 0);
        accO[1][n] = __builtin_amdgcn_mfma_f32_16x16x32_bf16(pa1, vb, accO[1][n], 0, 0, 0);
      }
    }
    __builtin_amdgcn_s_setprio(0);
  };

  int buf = 0;
  LOADT();
  WRITET(0);
  const int nkt = (q0 + 128) >> 6;
  for (int kt = 0; kt < nkt - 1; kt++) {
    __syncthreads();
    LOADT();
    TILE(buf, kt * 64);
    WRITET(buf ^ 1);
    buf ^= 1;
  }
  __syncthreads();
  TILE(buf, (nkt - 1) * 64);

  // epilogue: acc_l[u][r] already holds l for q-row kq*4+r (MFMA did the reduce)
#pragma unroll
  for (int u = 0; u < 2; u++) {
    const int qbu = u ? qb1 : qb0;
    float lr[4];
#pragma unroll
    for (int r = 0; r < 4; r++) lr[r] = 1.f / accl[u][r];
#pragma unroll
    for (int n = 0; n < 4; n++) {
#pragma unroll
      for (int r = 0; r < 4; r++) {
        int qrow = qbu + kq * 4 + r;
        float v = accO[u][n][r] * lr[r];
        att[((size_t)b * T + qrow) * C + h * 64 + n * 16 + r0] = f2bf(v);
      }
    }
  }
}

extern "C" void kernel_launch(void* const* d_in, const int* in_sizes, int n_in,
                              void* d_out, int out_size, void* d_ws, size_t ws_size,
                              hipStream_t stream) {
  const float* x = (const float*)d_in[0];
  const float* w_qkv = (const float*)d_in[1];
  const float* b_qkv = (const float*)d_in[2];
  const float* w_proj = (const float*)d_in[3];
  const float* b_proj = (const float*)d_in[4];

  constexpr int B = 4, T = 2048, C = 1024, C3 = 3072;
  constexpr int M = B * T;  // 8192
  constexpr float SCL = 0.125f * LOG2E;

  unsigned short* x_bf = (unsigned short*)d_ws;            // M*C
  unsigned short* wqkvT = x_bf + (size_t)M * C;            // C3*C
  unsigned short* wprojT = wqkvT + (size_t)C3 * C;         // C*C
  unsigned short* qkv = wprojT + (size_t)C * C;            // M*C3
  unsigned short* att = qkv + (size_t)M * C3;              // M*C
  float* bias_s = (float*)(att + (size_t)M * C);           // C3 floats

  hipLaunchKernelGGL(k_convert, dim3(2048), dim3(256), 0, stream, x, x_bf, M * C / 4);
  hipLaunchKernelGGL(k_transpose, dim3(C3 / 32, C / 32), dim3(256), 0, stream,
                     w_qkv, wqkvT, C, C3, C, SCL, b_qkv, bias_s);
  hipLaunchKernelGGL(k_transpose, dim3(C / 32, C / 32), dim3(256), 0, stream,
                     w_proj, wprojT, C, C, 0, 1.f, (const float*)nullptr, (float*)nullptr);
  hipLaunchKernelGGL((k_gemm<true>), dim3(M / 128, C3 / 128), dim3(256), 0, stream,
                     x_bf, wqkvT, bias_s, (void*)qkv, M, C3, C);
  hipLaunchKernelGGL(k_flash, dim3(64, 16), dim3(256), 0, stream, qkv, att, T);
  hipLaunchKernelGGL((k_gemm<false>), dim3(M / 128, C / 128), dim3(256), 0, stream,
                     att, wprojT, b_proj, d_out, M, C, C);
}